// Round 10
// baseline (173.560 us; speedup 1.0000x reference)
//
#include <hip/hip_runtime.h>
#include <stdint.h>

// Problem constants: B=16, C=48, H=W=64, N_CORR=2048
#define BB 16
#define HW 4096
#define NC 2048
// dbp: MFMA-fragment-ordered normalized bf16 columns, 96 B/col, no pad.
// Per image slab = 128 groups x 3072 B = 393216 B.
// Chunk mapping: col c, byte-offset bo (16B chunk = bo>>4 = hl + 2*ks):
//   addr = slab + (c>>5)*3072 + ks*1024 + (hl*32 + (c&31))*16 + (bo&15)
// so B-operand load for a wave (lane = hl*32+ml, col = g*32+ml, k-step ks) is
// ONE coalesced b128: slab + g*3072 + ks*1024 + lane*16.
#define IMGB 393216

typedef __attribute__((ext_vector_type(8))) __bf16 bf16x8;
typedef __attribute__((ext_vector_type(8))) short short8;
typedef __attribute__((ext_vector_type(4))) float floatx4;
typedef __attribute__((ext_vector_type(16))) float floatx16;

static __device__ __forceinline__ unsigned short f2bf(float f) {
    unsigned u = __builtin_bit_cast(unsigned, f);
    unsigned r = u + 0x7fffu + ((u >> 16) & 1u);    // RNE
    return (unsigned short)(r >> 16);
}

// fragment-layout address of byte bo of column c (bo 8-aligned usage)
static __device__ __forceinline__ const unsigned char*
frag_addr(const unsigned char* slab, int c, int bo) {
    int chunk = bo >> 4;
    return slab + (c >> 5) * 3072 + (chunk >> 1) * 1024 +
           (chunk & 1) * 512 + (c & 31) * 16 + (bo & 15);
}

// ---------------------------------------------------------------------------
// prep_fused:
//   blocks [0,512):   one (img,b,chunk): 256 cols x 48 fp32 coalesced reads
//                     (wave c-split), normalize, pack bf16 into the
//                     FRAGMENT-ORDERED LDS slab, coalesced copy-out to dbp.
//   blocks [512,544): counting sort of each (dir,b) query segment by qi
//   blocks [544,552): zero maxs2enc (atomicMax identity)
// ---------------------------------------------------------------------------
__global__ void prep_fused(const float* __restrict__ x1, const float* __restrict__ x2,
                           const int* __restrict__ ids, const int* __restrict__ fp2,
                           unsigned char* __restrict__ dbp,
                           int* __restrict__ perm, int* __restrict__ qcol_s,
                           int* __restrict__ aqpack, unsigned int* __restrict__ maxs2enc) {
    __shared__ __align__(16) unsigned char slab[24576 + 4096 + 1024];
    int bid = blockIdx.x, tid = threadIdx.x;
    if (bid < 512) {
        int img = bid >> 8;
        int b = (bid >> 4) & 15;
        int p0 = (bid & 15) * 256;
        int w = tid >> 6, l = tid & 63;
        const float* x = img ? x2 : x1;
        const float* base = x + ((size_t)b * 48 + w * 12) * HW + p0 + 4 * l;
        floatx4 v[12];
        floatx4 ps = {0.f, 0.f, 0.f, 0.f};
#pragma unroll
        for (int cc = 0; cc < 12; ++cc) {
            v[cc] = *(const floatx4*)(base + cc * HW);
#pragma unroll
            for (int q = 0; q < 4; ++q) ps[q] = fmaf(v[cc][q], v[cc][q], ps[q]);
        }
        float* psum = (float*)(slab + 24576);             // [4 waves][256 cols]
        float* rbuf = (float*)(slab + 24576 + 4096);      // [256 cols]
        *(floatx4*)(psum + w * 256 + 4 * l) = ps;
        __syncthreads();
        float s = psum[tid] + psum[256 + tid] + psum[512 + tid] + psum[768 + tid];
        rbuf[tid] = 1.f / fmaxf(sqrtf(s), 1e-12f);
        __syncthreads();
        floatx4 rv = *(const floatx4*)(rbuf + 4 * l);
#pragma unroll
        for (int q = 0; q < 4; ++q) {
            int c = 4 * l + q;                            // local col
            unsigned u[6];
#pragma unroll
            for (int p = 0; p < 6; ++p) {
                u[p] = (unsigned)f2bf(v[2 * p][q] * rv[q]) |
                       ((unsigned)f2bf(v[2 * p + 1][q] * rv[q]) << 16);
            }
            // wave w owns bytes [w*24, w*24+24) of col c's 96-B vector
#pragma unroll
            for (int p3 = 0; p3 < 3; ++p3) {
                int bo = w * 24 + 8 * p3;
                *(uint2*)frag_addr(slab, c, bo) = make_uint2(u[2 * p3], u[2 * p3 + 1]);
            }
        }
        __syncthreads();
        unsigned char* dstb = dbp + (size_t)(img * BB + b) * IMGB + (bid & 15) * 24576;
#pragma unroll
        for (int rr = 0; rr < 6; ++rr) {                  // 24576 B, coalesced
            int idx = rr * 4096 + tid * 16;
            *(floatx4*)(dstb + idx) = *(const floatx4*)(slab + idx);
        }
    } else if (bid < 544) {
        int* hist = (int*)slab;
        int* base = hist + 64;
        int seg = bid - 512;                      // dir*16 + b
        int dir = seg >> 4, b = seg & 15;
        if (tid < 64) hist[tid] = 0;
        __syncthreads();
#pragma unroll
        for (int k = 0; k < 8; ++k) {
            int n = k * 256 + tid;
            int idv = ids[b * NC + n];
            int i2 = fp2[b * 2 * NC + n];
            int qi = (dir == 0) ? i2 : (idv >> 6);
            atomicAdd(&hist[qi], 1);
        }
        __syncthreads();
        if (tid == 0) {
            int run = 0;
            for (int k = 0; k < 64; ++k) { base[k] = run; run += hist[k]; }
        }
        __syncthreads();
#pragma unroll
        for (int k = 0; k < 8; ++k) {
            int n = k * 256 + tid;
            int idv = ids[b * NC + n];
            int i2 = fp2[b * 2 * NC + n];
            int j2 = fp2[b * 2 * NC + NC + n];
            int qi, qj, qcol;
            if (dir == 0) { qi = i2; qj = j2; qcol = idv; }
            else          { qi = idv >> 6; qj = idv & 63; qcol = i2 * 64 + j2; }
            int slot = atomicAdd(&base[qi], 1);
            perm[seg * NC + slot] = n;
            qcol_s[seg * NC + slot] = qcol;
            aqpack[seg * NC + slot] = (qi << 8) | qj;
        }
    } else {
        int t = (bid - 544) * 256 + tid;          // [0, 2048)
        uint4* p = (uint4*)maxs2enc;
        uint4 z = {0u, 0u, 0u, 0u};
#pragma unroll
        for (int k = 0; k < 8; ++k) p[k * 2048 + t] = z;
    }
}

// ---------------------------------------------------------------------------
// maxscore_mfma: masked hardest-negative, 32x32x16 bf16 MFMA (K=48 native),
// NO LDS / NO BARRIERS (R9 post-mortem: barrier vmcnt drains, not pipes,
// were the wall). B-operands load as single coalesced b128 per (group,ks)
// straight from the fragment-ordered dbp (L2-hot), software-pipelined one
// group ahead. grid = 1024: seg = gid&31, mtile = (gid>>5)&7 (256 q),
// nq = gid>>8 (1024 cols = 32 groups). Wave owns 64 queries x all groups.
// C/D: col=lane&31, row=(reg&3)+8*(reg>>2)+4*(lane>>5) [m74/m101, R7-verified]
// ---------------------------------------------------------------------------
__global__ __launch_bounds__(256) void maxscore_mfma(
    const unsigned char* __restrict__ dbp,
    const int* __restrict__ perm, const int* __restrict__ qcol_s,
    const int* __restrict__ aqpack, unsigned int* __restrict__ maxs2enc) {
    int tid = threadIdx.x, wave = tid >> 6, lane = tid & 63;
    int ml = lane & 31, hl = lane >> 5;
    int gid = blockIdx.x;
    int seg = gid & 31, dir = seg >> 4, b = seg & 15;
    int rest = gid >> 5, mtile = rest & 7, nq = rest >> 3;   // nq in [0,4)
    int qbase = mtile * 256;

    const unsigned char* qsl = dbp + (size_t)(dir * BB + b) * IMGB;
    const unsigned char* dsl = dbp + (size_t)((1 - dir) * BB + b) * IMGB;

    // A-fragments: A[m=ml][k=hl*8+j]; chunk (ks,hl) of col qc.
    short8 afr[2][3];
#pragma unroll
    for (int mc = 0; mc < 2; ++mc) {
        int qc = qcol_s[seg * NC + qbase + wave * 64 + mc * 32 + ml];
        const unsigned char* cb = qsl + (qc >> 5) * 3072 + hl * 512 + (qc & 31) * 16;
        afr[mc][0] = *(const short8*)(cb);
        afr[mc][1] = *(const short8*)(cb + 1024);
        afr[mc][2] = *(const short8*)(cb + 2048);
    }
    // Anchors packed 2 per int: regs rr,rr+1; row(rr)=(rr&3)+8*(rr>>2)+4*hl
    int qp[2][8];
#pragma unroll
    for (int mc = 0; mc < 2; ++mc)
#pragma unroll
        for (int rp = 0; rp < 8; ++rp) {
            int rr = 2 * rp;
            int row = (rr & 3) + 8 * (rr >> 2) + 4 * hl;
            int slot = seg * NC + qbase + wave * 64 + mc * 32 + row;
            qp[mc][rp] = aqpack[slot] | (aqpack[slot + 1] << 16);
        }
    int wb = seg * NC + qbase + wave * 64;
    int qimin = __builtin_amdgcn_readfirstlane(aqpack[wb] >> 8);
    int qimax = __builtin_amdgcn_readfirstlane(aqpack[wb + 63] >> 8);

    const unsigned char* dB = dsl + nq * 32 * 3072;       // 32 groups of 32 cols
    // pipeline: prefetch group 0
    short8 nb0 = *(const short8*)(dB + lane * 16);
    short8 nb1 = *(const short8*)(dB + 1024 + lane * 16);
    short8 nb2 = *(const short8*)(dB + 2048 + lane * 16);

    float mx[2][16];
#pragma unroll
    for (int mc = 0; mc < 2; ++mc)
#pragma unroll
        for (int rr = 0; rr < 16; ++rr) mx[mc][rr] = -1e30f;
    float mlf = (float)ml;

    for (int g = 0; g < 32; ++g) {
        short8 b0 = nb0, b1 = nb1, b2 = nb2;
        if (g + 1 < 32) {                                 // prefetch next group
            const unsigned char* p = dB + (g + 1) * 3072 + lane * 16;
            nb0 = *(const short8*)(p);
            nb1 = *(const short8*)(p + 1024);
            nb2 = *(const short8*)(p + 2048);
        }
        int gg = nq * 32 + g;
        int mi = gg >> 1;                                 // db row (uniform)
        bool active = (mi >= qimin - 4) && (mi <= qimax + 4);   // wave-uniform
        float jml = (float)((gg & 1) * 32) + mlf;         // this lane's col j
        float mi_f = (float)mi;
#pragma unroll
        for (int mc = 0; mc < 2; ++mc) {
            floatx16 acc = {};
            acc = __builtin_amdgcn_mfma_f32_32x32x16_bf16(
                      __builtin_bit_cast(bf16x8, afr[mc][0]),
                      __builtin_bit_cast(bf16x8, b0), acc, 0, 0, 0);
            acc = __builtin_amdgcn_mfma_f32_32x32x16_bf16(
                      __builtin_bit_cast(bf16x8, afr[mc][1]),
                      __builtin_bit_cast(bf16x8, b1), acc, 0, 0, 0);
            acc = __builtin_amdgcn_mfma_f32_32x32x16_bf16(
                      __builtin_bit_cast(bf16x8, afr[mc][2]),
                      __builtin_bit_cast(bf16x8, b2), acc, 0, 0, 0);
            if (!active) {                                // fast: 1 op/elem
#pragma unroll
                for (int rr = 0; rr < 16; ++rr)
                    mx[mc][rr] = fmaxf(mx[mc][rr], acc[rr]);
            } else {                                      // rare: inline mask
#pragma unroll
                for (int rp = 0; rp < 8; ++rp) {
                    int ap2 = qp[mc][rp];
#pragma unroll
                    for (int h = 0; h < 2; ++h) {
                        int rr = 2 * rp + h;
                        int ap = (ap2 >> (16 * h)) & 0xffff;
                        bool rowblk = fabsf((float)(ap >> 8) - mi_f) <= 4.0f;
                        bool colblk = fabsf((float)(ap & 255) - jml) <= 4.0f;
                        bool ok = !(rowblk && colblk);
                        mx[mc][rr] = ok ? fmaxf(mx[mc][rr], acc[rr]) : mx[mc][rr];
                    }
                }
            }
        }
    }

    // reduce max over the 32 cols (lanes sharing hl)
#pragma unroll
    for (int mc = 0; mc < 2; ++mc)
#pragma unroll
        for (int rr = 0; rr < 16; ++rr) {
            float v = mx[mc][rr];
            v = fmaxf(v, __shfl_xor(v, 1, 32));
            v = fmaxf(v, __shfl_xor(v, 2, 32));
            v = fmaxf(v, __shfl_xor(v, 4, 32));
            v = fmaxf(v, __shfl_xor(v, 8, 32));
            v = fmaxf(v, __shfl_xor(v, 16, 32));
            mx[mc][rr] = v;
        }
    if (ml == 0) {                                        // lanes 0 and 32
#pragma unroll
        for (int mc = 0; mc < 2; ++mc)
#pragma unroll
            for (int rr = 0; rr < 16; ++rr) {
                int row = (rr & 3) + 8 * (rr >> 2) + 4 * hl;
                int slot = qbase + wave * 64 + mc * 32 + row;
                int orig = perm[seg * NC + slot];
                float v = mx[mc][rr] + 2.0f;              // > 0: uint-monotone
                atomicMax(&maxs2enc[(size_t)seg * NC + orig],
                          __builtin_bit_cast(unsigned, v));
            }
    }
}

// ---------------------------------------------------------------------------
// loss: pos-distance from the fragment-ordered bf16 cols (identical rounding
// to the neg path), decode/merge direction maxes, weighted partial sums.
// ---------------------------------------------------------------------------
__global__ void loss_kernel(const float* __restrict__ att1, const float* __restrict__ att2,
                            const int* __restrict__ ids, const int* __restrict__ fp2,
                            const unsigned char* __restrict__ dbp,
                            const unsigned int* __restrict__ maxs2enc,
                            float* __restrict__ pnum, float* __restrict__ pden) {
    int b = blockIdx.x >> 3, chunk = blockIdx.x & 7;
    int tid = threadIdx.x;
    int n = chunk * 256 + tid;
    int idv = ids[b * NC + n];
    int i2 = fp2[b * 2 * NC + n], j2 = fp2[b * 2 * NC + NC + n];
    int qc2 = i2 * 64 + j2;
    const unsigned char* s1 = dbp + (size_t)b * IMGB;             // img0
    const unsigned char* s2 = dbp + (size_t)(BB + b) * IMGB;      // img1
    float dot = 0.f;
#pragma unroll
    for (int k = 0; k < 12; ++k) {                        // 12 x 8 B = 48 bf16
        uint2 xa = *(const uint2*)frag_addr(s1, idv, 8 * k);
        uint2 xb = *(const uint2*)frag_addr(s2, qc2, 8 * k);
        const unsigned* xu = (const unsigned*)&xa;
        const unsigned* yu = (const unsigned*)&xb;
#pragma unroll
        for (int w = 0; w < 2; ++w) {
            float xl = __builtin_bit_cast(float, xu[w] << 16);
            float xh = __builtin_bit_cast(float, xu[w] & 0xffff0000u);
            float yl = __builtin_bit_cast(float, yu[w] << 16);
            float yh = __builtin_bit_cast(float, yu[w] & 0xffff0000u);
            dot = fmaf(xl, yl, fmaf(xh, yh, dot));
        }
    }
    float m0 = __builtin_bit_cast(float, maxs2enc[(size_t)(0 * BB + b) * NC + n]) - 2.0f;
    float m1 = __builtin_bit_cast(float, maxs2enc[(size_t)(1 * BB + b) * NC + n]) - 2.0f;
    float ms = fmaxf(m0, m1);
    float diff = (2.f - 2.f * dot) - (2.f - 2.f * ms);
    float w = att1[b * HW + idv] * att2[b * HW + qc2];
    float num = w * fmaxf(0.f, 1.f + diff);
    float den = w;
    __shared__ float sn[256], sd[256];
    sn[tid] = num; sd[tid] = den;
    __syncthreads();
    for (int s = 128; s > 0; s >>= 1) {
        if (tid < s) { sn[tid] += sn[tid + s]; sd[tid] += sd[tid + s]; }
        __syncthreads();
    }
    if (tid == 0) { pnum[blockIdx.x] = sn[0]; pden[blockIdx.x] = sd[0]; }
}

__global__ void final_kernel(const float* __restrict__ pnum, const float* __restrict__ pden,
                             float* __restrict__ out) {
    int tid = threadIdx.x;
    __shared__ float r[16];
    if (tid < 16) {
        float n = 0.f, d = 0.f;
#pragma unroll
        for (int c = 0; c < 8; ++c) { n += pnum[tid * 8 + c]; d += pden[tid * 8 + c]; }
        r[tid] = n / d;
    }
    __syncthreads();
    if (tid == 0) {
        float s = 0.f;
#pragma unroll
        for (int k = 0; k < 16; ++k) s += r[k];
        out[0] = s * (1.f / BB);
    }
}

extern "C" void kernel_launch(void* const* d_in, const int* in_sizes, int n_in,
                              void* d_out, int out_size, void* d_ws, size_t ws_size,
                              hipStream_t stream) {
    const float* x1  = (const float*)d_in[0];
    const float* x2  = (const float*)d_in[1];
    const float* att1 = (const float*)d_in[2];
    const float* att2 = (const float*)d_in[3];
    const int* ids   = (const int*)d_in[4];
    const int* fp2   = (const int*)d_in[5];
    float* out = (float*)d_out;

    // ws layout (bytes), ~13.6 MB. (R8: harness poisons the FULL d_ws
    // allocation regardless of use — sizing is perf-neutral.)
    unsigned char* w = (unsigned char*)d_ws;
    unsigned char* dbp = w;                                  // 2*16*393216 = 12,582,912
    int* perm    = (int*)(w + 12582912);                     // 32*2048*4 = 262,144
    int* qcol_s  = (int*)(w + 12845056);                     // 262,144
    int* aqpack  = (int*)(w + 13107200);                     // 262,144
    unsigned int* maxs2enc = (unsigned int*)(w + 13369344);  // 262,144
    float* pnum  = (float*)(w + 13631488);                   // 512
    float* pden  = (float*)(w + 13632000);                   // 512

    prep_fused<<<dim3(552), dim3(256), 0, stream>>>(x1, x2, ids, fp2, dbp,
                                                    perm, qcol_s, aqpack, maxs2enc);
    maxscore_mfma<<<dim3(1024), dim3(256), 0, stream>>>(dbp, perm, qcol_s, aqpack, maxs2enc);
    loss_kernel<<<dim3(128), dim3(256), 0, stream>>>(att1, att2, ids, fp2, dbp, maxs2enc, pnum, pden);
    final_kernel<<<dim3(1), dim3(64), 0, stream>>>(pnum, pden, out);
}

// Round 11
// 146.295 us; speedup vs baseline: 1.1864x; 1.1864x over previous
//
#include <hip/hip_runtime.h>
#include <stdint.h>

// Problem constants: B=16, C=48, H=W=64, N_CORR=2048
#define BB 16
#define HW 4096
#define NC 2048
#define KHW 72           // halfwords per column: 48 data + 16 zeros (K-pad to 64) + 8 pad
#define KB 144           // bytes per column (16B-aligned -> ds_read_b128)

typedef __attribute__((ext_vector_type(8))) __bf16 bf16x8;
typedef __attribute__((ext_vector_type(8))) short short8;
typedef __attribute__((ext_vector_type(4))) float floatx4;

static __device__ __forceinline__ unsigned short f2bf(float f) {
    unsigned u = __builtin_bit_cast(unsigned, f);
    unsigned r = u + 0x7fffu + ((u >> 16) & 1u);    // RNE
    return (unsigned short)(r >> 16);
}

#define GLD16(g, l) __builtin_amdgcn_global_load_lds((const __attribute__((address_space(1))) void*)(g), (__attribute__((address_space(3))) void*)(l), 16, 0, 0)
#define GLD4(g, l)  __builtin_amdgcn_global_load_lds((const __attribute__((address_space(1))) void*)(g), (__attribute__((address_space(3))) void*)(l), 4, 0, 0)

// ---------------------------------------------------------------------------
// prep_fused:
//   blocks [0,512):   one (img,b,chunk): 256 cols x 48 fp32 coalesced reads
//                     (wave c-split float4), normalize, pack bf16 into LDS
//                     slab (KB=144, K-pad zeros), coalesced copy-out to dbp.
//   blocks [512,544): counting sort of each (dir,b) query segment by qi.
// (maxs2enc zeroing dropped: maxscore now writes every slice slot directly.)
// ---------------------------------------------------------------------------
__global__ void prep_fused(const float* __restrict__ x1, const float* __restrict__ x2,
                           const int* __restrict__ ids, const int* __restrict__ fp2,
                           unsigned short* __restrict__ dbp,
                           int* __restrict__ perm, int* __restrict__ qcol_s,
                           int* __restrict__ aqpack) {
    __shared__ __align__(16) unsigned char slab[36864 + 4096 + 1024];
    int bid = blockIdx.x, tid = threadIdx.x;
    if (bid < 512) {
        int img = bid >> 8;
        int b = (bid >> 4) & 15;
        int p0 = (bid & 15) * 256;
        int w = tid >> 6, l = tid & 63;
        const float* x = img ? x2 : x1;
        const float* base = x + ((size_t)b * 48 + w * 12) * HW + p0 + 4 * l;
        floatx4 v[12];
        floatx4 ps = {0.f, 0.f, 0.f, 0.f};
#pragma unroll
        for (int cc = 0; cc < 12; ++cc) {
            v[cc] = *(const floatx4*)(base + cc * HW);
#pragma unroll
            for (int q = 0; q < 4; ++q) ps[q] = fmaf(v[cc][q], v[cc][q], ps[q]);
        }
        float* psum = (float*)(slab + 36864);             // [4 waves][256 cols]
        float* rbuf = (float*)(slab + 36864 + 4096);      // [256 cols]
        *(floatx4*)(psum + w * 256 + 4 * l) = ps;
        __syncthreads();
        float s = psum[tid] + psum[256 + tid] + psum[512 + tid] + psum[768 + tid];
        rbuf[tid] = 1.f / fmaxf(sqrtf(s), 1e-12f);
        __syncthreads();
        floatx4 rv = *(const floatx4*)(rbuf + 4 * l);
#pragma unroll
        for (int q = 0; q < 4; ++q) {
            unsigned u[6];
#pragma unroll
            for (int p = 0; p < 6; ++p) {
                u[p] = (unsigned)f2bf(v[2 * p][q] * rv[q]) |
                       ((unsigned)f2bf(v[2 * p + 1][q] * rv[q]) << 16);
            }
            unsigned char* dst = slab + (4 * l + q) * KB + w * 24;  // 8-aligned
            *(uint2*)(dst + 0)  = make_uint2(u[0], u[1]);
            *(uint2*)(dst + 8)  = make_uint2(u[2], u[3]);
            *(uint2*)(dst + 16) = make_uint2(u[4], u[5]);
        }
        uint4 z4 = {0u, 0u, 0u, 0u};
#pragma unroll
        for (int z = 0; z < 3; ++z)                       // K-pad zeros
            *(uint4*)(slab + tid * KB + 96 + z * 16) = z4;
        __syncthreads();
        unsigned char* dstb = (unsigned char*)dbp + ((size_t)(img * BB + b) * HW + p0) * KB;
#pragma unroll
        for (int rr = 0; rr < 9; ++rr) {                  // 256*144 B, coalesced
            int idx = rr * 4096 + tid * 16;
            *(floatx4*)(dstb + idx) = *(const floatx4*)(slab + idx);
        }
    } else {
        int* hist = (int*)slab;
        int* base = hist + 64;
        int seg = bid - 512;                      // dir*16 + b
        int dir = seg >> 4, b = seg & 15;
        if (tid < 64) hist[tid] = 0;
        __syncthreads();
#pragma unroll
        for (int k = 0; k < 8; ++k) {
            int n = k * 256 + tid;
            int idv = ids[b * NC + n];
            int i2 = fp2[b * 2 * NC + n];
            int qi = (dir == 0) ? i2 : (idv >> 6);
            atomicAdd(&hist[qi], 1);
        }
        __syncthreads();
        if (tid == 0) {
            int run = 0;
            for (int k = 0; k < 64; ++k) { base[k] = run; run += hist[k]; }
        }
        __syncthreads();
#pragma unroll
        for (int k = 0; k < 8; ++k) {
            int n = k * 256 + tid;
            int idv = ids[b * NC + n];
            int i2 = fp2[b * 2 * NC + n];
            int j2 = fp2[b * 2 * NC + NC + n];
            int qi, qj, qcol;
            if (dir == 0) { qi = i2; qj = j2; qcol = idv; }
            else          { qi = idv >> 6; qj = idv & 63; qcol = i2 * 64 + j2; }
            int slot = atomicAdd(&base[qi], 1);
            perm[seg * NC + slot] = n;
            qcol_s[seg * NC + slot] = qcol;
            aqpack[seg * NC + slot] = (qi << 8) | qj;
        }
    }
}

// ---------------------------------------------------------------------------
// maxscore_mfma — the measured champion (R3-proposal, 52.3 us, VGPR 64,
// Occ 29%), restored byte-for-byte except: direct per-slice stores replace
// atomicMax (disjoint writers across mtile blocks -> deterministic, no init).
// grid = 1024: seg = gid&31, mtile = (gid>>5)&7 (256 q), nq = gid>>8 (1024
// cols). 8 double-buffered 128-col LDS tiles via global_load_lds; 16x16x32
// bf16 MFMA, K=64 zero-padded; sorted queries -> wave-uniform row-mask fast
// path (1 op/elem). Five alternative structures (smaller tiles R5, wave-
// private R6, packed-in-place 32x32 R7, K=48 32x32 R9, no-LDS 32x32 R10)
// all measured slower; the barrier vmcnt drain is the plateau (m97-class).
// ---------------------------------------------------------------------------
static __device__ __forceinline__ void dma_tile(const unsigned char* g, unsigned char* l,
                                                int wave, int lane) {
#pragma unroll
    for (int rr = 0; rr < 4; ++rr)
        GLD16(g + rr * 4096 + wave * 1024 + lane * 16, l + rr * 4096 + wave * 1024);
#pragma unroll
    for (int rr = 0; rr < 2; ++rr)
        GLD4(g + 16384 + rr * 1024 + wave * 256 + lane * 4, l + 16384 + rr * 1024 + wave * 256);
}

__global__ __launch_bounds__(256) void maxscore_mfma(
    const unsigned short* __restrict__ dbp,
    const int* __restrict__ perm, const int* __restrict__ qcol_s,
    const int* __restrict__ aqpack, float* __restrict__ maxs2) {
    __shared__ __align__(16) unsigned char smem[36864];   // 2 db buffers of 18432

    int tid = threadIdx.x, wave = tid >> 6, lane = tid & 63;
    int quad = lane >> 4, cl = lane & 15;
    int gid = blockIdx.x;
    int seg = gid & 31, dir = seg >> 4, b = seg & 15;
    int rest = gid >> 5, mtile = rest & 7, nq = rest >> 3;   // nq in [0,4)
    int qbase = mtile * 256;
    int dbimg = 1 - dir;

    // A-fragments: 16B gathers straight from dbp (query image = dir; L2-hot)
    const unsigned char* dbQ = (const unsigned char*)(dbp + (size_t)(dir * BB + b) * HW * KHW);
    short8 afr[4][2];
#pragma unroll
    for (int t = 0; t < 4; ++t) {
        int slot = qbase + wave * 64 + t * 16 + cl;       // A[m=lane&15]
        int qc = qcol_s[seg * NC + slot];
        const unsigned char* src = dbQ + (size_t)qc * KB;
        afr[t][0] = *(const short8*)(src + quad * 16);
        afr[t][1] = *(const short8*)(src + 64 + quad * 16);
    }
    // Anchors for this lane's C/D rows (row = quad*4+r)
    float qif[4][4], qjc[4][4];
    float cl_f = (float)cl;
#pragma unroll
    for (int t = 0; t < 4; ++t)
#pragma unroll
        for (int r = 0; r < 4; ++r) {
            int slot = qbase + wave * 64 + t * 16 + quad * 4 + r;
            int ap = aqpack[seg * NC + slot];
            qif[t][r] = (float)(ap >> 8);
            qjc[t][r] = (float)(ap & 255) - cl_f;         // qj - lane col offset
        }
    // Wave's sorted qi range
    int wb = seg * NC + qbase + wave * 64;
    int qimin = __builtin_amdgcn_readfirstlane(aqpack[wb] >> 8);
    int qimax = __builtin_amdgcn_readfirstlane(aqpack[wb + 63] >> 8);

    const unsigned char* dsrc =
        (const unsigned char*)(dbp + ((size_t)(dbimg * BB + b) * HW + nq * 1024) * KHW);
    dma_tile(dsrc, smem, wave, lane);                     // prefetch tile 0

    const floatx4 zf = {0.f, 0.f, 0.f, 0.f};
    float mx[4][4];
#pragma unroll
    for (int t = 0; t < 4; ++t)
#pragma unroll
        for (int r = 0; r < 4; ++r) mx[t][r] = -1e30f;

    for (int tile = 0; tile < 8; ++tile) {
        unsigned char* buf = smem + (tile & 1) * 18432;
        __syncthreads();
        if (tile + 1 < 8)
            dma_tile(dsrc + (tile + 1) * 18432, smem + ((tile + 1) & 1) * 18432, wave, lane);
        int mi0 = (nq * 1024 + tile * 128) >> 6;          // two db rows per tile
#pragma unroll
        for (int half = 0; half < 2; ++half) {
            int mi = mi0 + half;
            bool active = (mi >= qimin - 4) && (mi <= qimax + 4);   // wave-uniform
            if (active) {
                float mi_f = (float)mi;
                bool rowok[4][4];
#pragma unroll
                for (int t = 0; t < 4; ++t)
#pragma unroll
                    for (int r = 0; r < 4; ++r)
                        rowok[t][r] = fabsf(qif[t][r] - mi_f) > 4.0f;
#pragma unroll
                for (int js = 0; js < 4; ++js) {
                    int sub = half * 4 + js;
                    float jj = (float)(js * 16);
                    short8 b0 = *(const short8*)(buf + (sub * 16 + cl) * KB + quad * 16);
                    short8 b1 = *(const short8*)(buf + (sub * 16 + cl) * KB + 64 + quad * 16);
#pragma unroll
                    for (int t = 0; t < 4; ++t) {
                        floatx4 acc = __builtin_amdgcn_mfma_f32_16x16x32_bf16(
                            __builtin_bit_cast(bf16x8, afr[t][0]),
                            __builtin_bit_cast(bf16x8, b0), zf, 0, 0, 0);
                        acc = __builtin_amdgcn_mfma_f32_16x16x32_bf16(
                            __builtin_bit_cast(bf16x8, afr[t][1]),
                            __builtin_bit_cast(bf16x8, b1), acc, 0, 0, 0);
#pragma unroll
                        for (int r = 0; r < 4; ++r) {
                            float dj = qjc[t][r] - jj;
                            bool ok = rowok[t][r] || (fabsf(dj) > 4.0f);
                            mx[t][r] = ok ? fmaxf(mx[t][r], acc[r]) : mx[t][r];
                        }
                    }
                }
            } else {                                      // all rows allowed: 1 op/elem
#pragma unroll
                for (int js = 0; js < 4; ++js) {
                    int sub = half * 4 + js;
                    short8 b0 = *(const short8*)(buf + (sub * 16 + cl) * KB + quad * 16);
                    short8 b1 = *(const short8*)(buf + (sub * 16 + cl) * KB + 64 + quad * 16);
#pragma unroll
                    for (int t = 0; t < 4; ++t) {
                        floatx4 acc = __builtin_amdgcn_mfma_f32_16x16x32_bf16(
                            __builtin_bit_cast(bf16x8, afr[t][0]),
                            __builtin_bit_cast(bf16x8, b0), zf, 0, 0, 0);
                        acc = __builtin_amdgcn_mfma_f32_16x16x32_bf16(
                            __builtin_bit_cast(bf16x8, afr[t][1]),
                            __builtin_bit_cast(bf16x8, b1), acc, 0, 0, 0);
#pragma unroll
                        for (int r = 0; r < 4; ++r)
                            mx[t][r] = fmaxf(mx[t][r], acc[r]);
                    }
                }
            }
        }
    }

    // reduce max over the 16 lanes of each quad (disjoint col subsets)
#pragma unroll
    for (int t = 0; t < 4; ++t)
#pragma unroll
        for (int r = 0; r < 4; ++r) {
            float v = mx[t][r];
            v = fmaxf(v, __shfl_xor(v, 1, 16));
            v = fmaxf(v, __shfl_xor(v, 2, 16));
            v = fmaxf(v, __shfl_xor(v, 4, 16));
            v = fmaxf(v, __shfl_xor(v, 8, 16));
            mx[t][r] = v;
        }
    if (cl == 0) {                                        // 4 lanes per wave
#pragma unroll
        for (int t = 0; t < 4; ++t)
#pragma unroll
            for (int r = 0; r < 4; ++r) {
                int slot = qbase + wave * 64 + t * 16 + quad * 4 + r;
                int orig = perm[seg * NC + slot];
                // direct slice store: (nq,seg) slices have disjoint orig sets
                maxs2[((size_t)(nq * 32 + seg)) * NC + orig] = mx[t][r];
            }
    }
}

// ---------------------------------------------------------------------------
// loss: pos-distance from dbp bf16 columns (consistent rounding with the neg
// path), merge 8 slices (4 nq x 2 dir), weighted partial sums. grid = 128.
// ---------------------------------------------------------------------------
__global__ void loss_kernel(const float* __restrict__ att1, const float* __restrict__ att2,
                            const int* __restrict__ ids, const int* __restrict__ fp2,
                            const unsigned short* __restrict__ dbp,
                            const float* __restrict__ maxs2,
                            float* __restrict__ pnum, float* __restrict__ pden) {
    int b = blockIdx.x >> 3, chunk = blockIdx.x & 7;
    int tid = threadIdx.x;
    int n = chunk * 256 + tid;
    int idv = ids[b * NC + n];
    int i2 = fp2[b * 2 * NC + n], j2 = fp2[b * 2 * NC + NC + n];
    const uint4* a4 = (const uint4*)(dbp + ((size_t)(0 * BB + b) * HW + idv) * KHW);
    const uint4* b4 = (const uint4*)(dbp + ((size_t)(1 * BB + b) * HW + i2 * 64 + j2) * KHW);
    float dot = 0.f;
#pragma unroll
    for (int i = 0; i < 6; ++i) {                         // 6 x 16 B = 48 bf16
        uint4 xa = a4[i], xb = b4[i];
        const unsigned* xu = (const unsigned*)&xa;
        const unsigned* yu = (const unsigned*)&xb;
#pragma unroll
        for (int w = 0; w < 4; ++w) {
            float xl = __builtin_bit_cast(float, xu[w] << 16);
            float xh = __builtin_bit_cast(float, xu[w] & 0xffff0000u);
            float yl = __builtin_bit_cast(float, yu[w] << 16);
            float yh = __builtin_bit_cast(float, yu[w] & 0xffff0000u);
            dot = fmaf(xl, yl, fmaf(xh, yh, dot));
        }
    }
    float ms = -1e30f;
#pragma unroll
    for (int s8 = 0; s8 < 8; ++s8) {                      // nq = s8>>1, dir = s8&1
        int slice = (s8 >> 1) * 32 + (s8 & 1) * BB + b;
        ms = fmaxf(ms, maxs2[(size_t)slice * NC + n]);
    }
    float diff = (2.f - 2.f * dot) - (2.f - 2.f * ms);
    float w = att1[b * HW + idv] * att2[b * HW + i2 * 64 + j2];
    float num = w * fmaxf(0.f, 1.f + diff);
    float den = w;
    __shared__ float sn[256], sd[256];
    sn[tid] = num; sd[tid] = den;
    __syncthreads();
    for (int s = 128; s > 0; s >>= 1) {
        if (tid < s) { sn[tid] += sn[tid + s]; sd[tid] += sd[tid + s]; }
        __syncthreads();
    }
    if (tid == 0) { pnum[blockIdx.x] = sn[0]; pden[blockIdx.x] = sd[0]; }
}

__global__ void final_kernel(const float* __restrict__ pnum, const float* __restrict__ pden,
                             float* __restrict__ out) {
    int tid = threadIdx.x;
    __shared__ float r[16];
    if (tid < 16) {
        float n = 0.f, d = 0.f;
#pragma unroll
        for (int c = 0; c < 8; ++c) { n += pnum[tid * 8 + c]; d += pden[tid * 8 + c]; }
        r[tid] = n / d;
    }
    __syncthreads();
    if (tid == 0) {
        float s = 0.f;
#pragma unroll
        for (int k = 0; k < 16; ++k) s += r[k];
        out[0] = s * (1.f / BB);
    }
}

extern "C" void kernel_launch(void* const* d_in, const int* in_sizes, int n_in,
                              void* d_out, int out_size, void* d_ws, size_t ws_size,
                              hipStream_t stream) {
    const float* x1  = (const float*)d_in[0];
    const float* x2  = (const float*)d_in[1];
    const float* att1 = (const float*)d_in[2];
    const float* att2 = (const float*)d_in[3];
    const int* ids   = (const int*)d_in[4];
    const int* fp2   = (const int*)d_in[5];
    float* out = (float*)d_out;

    // ws layout (bytes), ~20.7 MB. (R8 finding: the harness poisons the FULL
    // d_ws allocation every iteration (~44 us) regardless of use — ws sizing
    // is perf-neutral.)
    unsigned char* w = (unsigned char*)d_ws;
    unsigned short* dbp = (unsigned short*)(w + 0);          // 2*16*4096*144 = 18,874,368
    int* perm    = (int*)(w + 18874368);                     // 32*2048*4 = 262,144
    int* qcol_s  = (int*)(w + 19136512);                     // 262,144
    int* aqpack  = (int*)(w + 19398656);                     // 262,144
    float* maxs2 = (float*)(w + 19660800);                   // 4*32*2048*4 = 1,048,576
    float* pnum  = (float*)(w + 20709376);                   // 512
    float* pden  = (float*)(w + 20709888);                   // 512

    prep_fused<<<dim3(544), dim3(256), 0, stream>>>(x1, x2, ids, fp2, dbp,
                                                    perm, qcol_s, aqpack);
    maxscore_mfma<<<dim3(1024), dim3(256), 0, stream>>>(dbp, perm, qcol_s, aqpack, maxs2);
    loss_kernel<<<dim3(128), dim3(256), 0, stream>>>(att1, att2, ids, fp2, dbp, maxs2, pnum, pden);
    final_kernel<<<dim3(1), dim3(64), 0, stream>>>(pnum, pden, out);
}

// Round 12
// 130.538 us; speedup vs baseline: 1.3296x; 1.1207x over previous
//
#include <hip/hip_runtime.h>
#include <stdint.h>

// Problem constants: B=16, C=48, H=W=64, N_CORR=2048
#define BB 16
#define HW 4096
#define NC 2048
#define KHW 72           // halfwords per column: 48 data + 16 zeros (K-pad to 64) + 8 pad
#define KB 144           // bytes per column (16B-aligned -> ds_read_b128)

typedef __attribute__((ext_vector_type(8))) __bf16 bf16x8;
typedef __attribute__((ext_vector_type(8))) short short8;
typedef __attribute__((ext_vector_type(4))) float floatx4;

static __device__ __forceinline__ unsigned short f2bf(float f) {
    unsigned u = __builtin_bit_cast(unsigned, f);
    unsigned r = u + 0x7fffu + ((u >> 16) & 1u);    // RNE
    return (unsigned short)(r >> 16);
}

#define GLD16(g, l) __builtin_amdgcn_global_load_lds((const __attribute__((address_space(1))) void*)(g), (__attribute__((address_space(3))) void*)(l), 16, 0, 0)
#define GLD4(g, l)  __builtin_amdgcn_global_load_lds((const __attribute__((address_space(1))) void*)(g), (__attribute__((address_space(3))) void*)(l), 4, 0, 0)

// ---------------------------------------------------------------------------
// prep_fused (R8-measured form):
//   blocks [0,512):   one (img,b,chunk): 256 cols x 48 fp32 coalesced reads
//                     (wave c-split float4), normalize, pack bf16 into LDS
//                     slab (KB=144, K-pad zeros), coalesced copy-out to dbp.
//   blocks [512,544): counting sort of each (dir,b) query segment by qi.
//   blocks [544,552): zero maxs2enc (atomicMax identity).
// ---------------------------------------------------------------------------
__global__ void prep_fused(const float* __restrict__ x1, const float* __restrict__ x2,
                           const int* __restrict__ ids, const int* __restrict__ fp2,
                           unsigned short* __restrict__ dbp,
                           int* __restrict__ perm, int* __restrict__ qcol_s,
                           int* __restrict__ aqpack, unsigned int* __restrict__ maxs2enc) {
    __shared__ __align__(16) unsigned char slab[36864 + 4096 + 1024];
    int bid = blockIdx.x, tid = threadIdx.x;
    if (bid < 512) {
        int img = bid >> 8;
        int b = (bid >> 4) & 15;
        int p0 = (bid & 15) * 256;
        int w = tid >> 6, l = tid & 63;
        const float* x = img ? x2 : x1;
        const float* base = x + ((size_t)b * 48 + w * 12) * HW + p0 + 4 * l;
        floatx4 v[12];
        floatx4 ps = {0.f, 0.f, 0.f, 0.f};
#pragma unroll
        for (int cc = 0; cc < 12; ++cc) {
            v[cc] = *(const floatx4*)(base + cc * HW);
#pragma unroll
            for (int q = 0; q < 4; ++q) ps[q] = fmaf(v[cc][q], v[cc][q], ps[q]);
        }
        float* psum = (float*)(slab + 36864);             // [4 waves][256 cols]
        float* rbuf = (float*)(slab + 36864 + 4096);      // [256 cols]
        *(floatx4*)(psum + w * 256 + 4 * l) = ps;
        __syncthreads();
        float s = psum[tid] + psum[256 + tid] + psum[512 + tid] + psum[768 + tid];
        rbuf[tid] = 1.f / fmaxf(sqrtf(s), 1e-12f);
        __syncthreads();
        floatx4 rv = *(const floatx4*)(rbuf + 4 * l);
#pragma unroll
        for (int q = 0; q < 4; ++q) {
            unsigned u[6];
#pragma unroll
            for (int p = 0; p < 6; ++p) {
                u[p] = (unsigned)f2bf(v[2 * p][q] * rv[q]) |
                       ((unsigned)f2bf(v[2 * p + 1][q] * rv[q]) << 16);
            }
            unsigned char* dst = slab + (4 * l + q) * KB + w * 24;  // 8-aligned
            *(uint2*)(dst + 0)  = make_uint2(u[0], u[1]);
            *(uint2*)(dst + 8)  = make_uint2(u[2], u[3]);
            *(uint2*)(dst + 16) = make_uint2(u[4], u[5]);
        }
        uint4 z4 = {0u, 0u, 0u, 0u};
#pragma unroll
        for (int z = 0; z < 3; ++z)                       // K-pad zeros
            *(uint4*)(slab + tid * KB + 96 + z * 16) = z4;
        __syncthreads();
        unsigned char* dstb = (unsigned char*)dbp + ((size_t)(img * BB + b) * HW + p0) * KB;
#pragma unroll
        for (int rr = 0; rr < 9; ++rr) {                  // 256*144 B, coalesced
            int idx = rr * 4096 + tid * 16;
            *(floatx4*)(dstb + idx) = *(const floatx4*)(slab + idx);
        }
    } else if (bid < 544) {
        int* hist = (int*)slab;
        int* base = hist + 64;
        int seg = bid - 512;                      // dir*16 + b
        int dir = seg >> 4, b = seg & 15;
        if (tid < 64) hist[tid] = 0;
        __syncthreads();
#pragma unroll
        for (int k = 0; k < 8; ++k) {
            int n = k * 256 + tid;
            int idv = ids[b * NC + n];
            int i2 = fp2[b * 2 * NC + n];
            int qi = (dir == 0) ? i2 : (idv >> 6);
            atomicAdd(&hist[qi], 1);
        }
        __syncthreads();
        if (tid == 0) {
            int run = 0;
            for (int k = 0; k < 64; ++k) { base[k] = run; run += hist[k]; }
        }
        __syncthreads();
#pragma unroll
        for (int k = 0; k < 8; ++k) {
            int n = k * 256 + tid;
            int idv = ids[b * NC + n];
            int i2 = fp2[b * 2 * NC + n];
            int j2 = fp2[b * 2 * NC + NC + n];
            int qi, qj, qcol;
            if (dir == 0) { qi = i2; qj = j2; qcol = idv; }
            else          { qi = idv >> 6; qj = idv & 63; qcol = i2 * 64 + j2; }
            int slot = atomicAdd(&base[qi], 1);
            perm[seg * NC + slot] = n;
            qcol_s[seg * NC + slot] = qcol;
            aqpack[seg * NC + slot] = (qi << 8) | qj;
        }
    } else {
        int t = (bid - 544) * 256 + tid;          // [0, 2048)
        uint4* p = (uint4*)maxs2enc;              // 16384 uint4 total
        uint4 z = {0u, 0u, 0u, 0u};
#pragma unroll
        for (int k = 0; k < 8; ++k) p[k * 2048 + t] = z;
    }
}

// ---------------------------------------------------------------------------
// maxscore_mfma — EXACT champion restore (R3-measured: 52.3 us, VGPR 64,
// Occ 29%): __launch_bounds__(256, 4), atomicMax monotone-encoded merge.
// grid = 1024: seg = gid&31, mtile = (gid>>5)&7 (256 q), nq = gid>>8 (1024
// cols). 8 double-buffered 128-col LDS tiles via global_load_lds; 16x16x32
// bf16 MFMA, K=64 zero-padded; sorted queries -> wave-uniform row-mask fast
// path. (R11 lesson: plain launch_bounds + direct stores measured 68 us —
// restore the exact measured spec before concluding anything.)
// ---------------------------------------------------------------------------
static __device__ __forceinline__ void dma_tile(const unsigned char* g, unsigned char* l,
                                                int wave, int lane) {
#pragma unroll
    for (int rr = 0; rr < 4; ++rr)
        GLD16(g + rr * 4096 + wave * 1024 + lane * 16, l + rr * 4096 + wave * 1024);
#pragma unroll
    for (int rr = 0; rr < 2; ++rr)
        GLD4(g + 16384 + rr * 1024 + wave * 256 + lane * 4, l + 16384 + rr * 1024 + wave * 256);
}

__global__ __launch_bounds__(256, 4) void maxscore_mfma(
    const unsigned short* __restrict__ dbp,
    const int* __restrict__ perm, const int* __restrict__ qcol_s,
    const int* __restrict__ aqpack, unsigned int* __restrict__ maxs2enc) {
    __shared__ __align__(16) unsigned char smem[36864];   // 2 db buffers of 18432

    int tid = threadIdx.x, wave = tid >> 6, lane = tid & 63;
    int quad = lane >> 4, cl = lane & 15;
    int gid = blockIdx.x;
    int seg = gid & 31, dir = seg >> 4, b = seg & 15;
    int rest = gid >> 5, mtile = rest & 7, nq = rest >> 3;   // nq in [0,4)
    int qbase = mtile * 256;
    int dbimg = 1 - dir;

    // A-fragments: 16B gathers straight from dbp (query image = dir; L2-hot)
    const unsigned char* dbQ = (const unsigned char*)(dbp + (size_t)(dir * BB + b) * HW * KHW);
    short8 afr[4][2];
#pragma unroll
    for (int t = 0; t < 4; ++t) {
        int slot = qbase + wave * 64 + t * 16 + cl;       // A[m=lane&15]
        int qc = qcol_s[seg * NC + slot];
        const unsigned char* src = dbQ + (size_t)qc * KB;
        afr[t][0] = *(const short8*)(src + quad * 16);
        afr[t][1] = *(const short8*)(src + 64 + quad * 16);
    }
    // Anchors for this lane's C/D rows (row = quad*4+r)
    float qif[4][4], qjc[4][4];
    float cl_f = (float)cl;
#pragma unroll
    for (int t = 0; t < 4; ++t)
#pragma unroll
        for (int r = 0; r < 4; ++r) {
            int slot = qbase + wave * 64 + t * 16 + quad * 4 + r;
            int ap = aqpack[seg * NC + slot];
            qif[t][r] = (float)(ap >> 8);
            qjc[t][r] = (float)(ap & 255) - cl_f;         // qj - lane col offset
        }
    // Wave's sorted qi range
    int wb = seg * NC + qbase + wave * 64;
    int qimin = __builtin_amdgcn_readfirstlane(aqpack[wb] >> 8);
    int qimax = __builtin_amdgcn_readfirstlane(aqpack[wb + 63] >> 8);

    const unsigned char* dsrc =
        (const unsigned char*)(dbp + ((size_t)(dbimg * BB + b) * HW + nq * 1024) * KHW);
    dma_tile(dsrc, smem, wave, lane);                     // prefetch tile 0

    const floatx4 zf = {0.f, 0.f, 0.f, 0.f};
    float mx[4][4];
#pragma unroll
    for (int t = 0; t < 4; ++t)
#pragma unroll
        for (int r = 0; r < 4; ++r) mx[t][r] = -1e30f;

    for (int tile = 0; tile < 8; ++tile) {
        unsigned char* buf = smem + (tile & 1) * 18432;
        __syncthreads();
        if (tile + 1 < 8)
            dma_tile(dsrc + (tile + 1) * 18432, smem + ((tile + 1) & 1) * 18432, wave, lane);
        int mi0 = (nq * 1024 + tile * 128) >> 6;          // two db rows per tile
#pragma unroll
        for (int half = 0; half < 2; ++half) {
            int mi = mi0 + half;
            bool active = (mi >= qimin - 4) && (mi <= qimax + 4);   // wave-uniform
            if (active) {
                float mi_f = (float)mi;
                bool rowok[4][4];
#pragma unroll
                for (int t = 0; t < 4; ++t)
#pragma unroll
                    for (int r = 0; r < 4; ++r)
                        rowok[t][r] = fabsf(qif[t][r] - mi_f) > 4.0f;
#pragma unroll
                for (int js = 0; js < 4; ++js) {
                    int sub = half * 4 + js;
                    float jj = (float)(js * 16);
                    short8 b0 = *(const short8*)(buf + (sub * 16 + cl) * KB + quad * 16);
                    short8 b1 = *(const short8*)(buf + (sub * 16 + cl) * KB + 64 + quad * 16);
#pragma unroll
                    for (int t = 0; t < 4; ++t) {
                        floatx4 acc = __builtin_amdgcn_mfma_f32_16x16x32_bf16(
                            __builtin_bit_cast(bf16x8, afr[t][0]),
                            __builtin_bit_cast(bf16x8, b0), zf, 0, 0, 0);
                        acc = __builtin_amdgcn_mfma_f32_16x16x32_bf16(
                            __builtin_bit_cast(bf16x8, afr[t][1]),
                            __builtin_bit_cast(bf16x8, b1), acc, 0, 0, 0);
#pragma unroll
                        for (int r = 0; r < 4; ++r) {
                            float dj = qjc[t][r] - jj;
                            bool ok = rowok[t][r] || (fabsf(dj) > 4.0f);
                            mx[t][r] = ok ? fmaxf(mx[t][r], acc[r]) : mx[t][r];
                        }
                    }
                }
            } else {                                      // all rows allowed: 1 op/elem
#pragma unroll
                for (int js = 0; js < 4; ++js) {
                    int sub = half * 4 + js;
                    short8 b0 = *(const short8*)(buf + (sub * 16 + cl) * KB + quad * 16);
                    short8 b1 = *(const short8*)(buf + (sub * 16 + cl) * KB + 64 + quad * 16);
#pragma unroll
                    for (int t = 0; t < 4; ++t) {
                        floatx4 acc = __builtin_amdgcn_mfma_f32_16x16x32_bf16(
                            __builtin_bit_cast(bf16x8, afr[t][0]),
                            __builtin_bit_cast(bf16x8, b0), zf, 0, 0, 0);
                        acc = __builtin_amdgcn_mfma_f32_16x16x32_bf16(
                            __builtin_bit_cast(bf16x8, afr[t][1]),
                            __builtin_bit_cast(bf16x8, b1), acc, 0, 0, 0);
#pragma unroll
                        for (int r = 0; r < 4; ++r)
                            mx[t][r] = fmaxf(mx[t][r], acc[r]);
                    }
                }
            }
        }
    }

    // reduce max over the 16 lanes of each quad (disjoint col subsets)
#pragma unroll
    for (int t = 0; t < 4; ++t)
#pragma unroll
        for (int r = 0; r < 4; ++r) {
            float v = mx[t][r];
            v = fmaxf(v, __shfl_xor(v, 1, 16));
            v = fmaxf(v, __shfl_xor(v, 2, 16));
            v = fmaxf(v, __shfl_xor(v, 4, 16));
            v = fmaxf(v, __shfl_xor(v, 8, 16));
            mx[t][r] = v;
        }
    if (cl == 0) {
#pragma unroll
        for (int t = 0; t < 4; ++t)
#pragma unroll
            for (int r = 0; r < 4; ++r) {
                int slot = qbase + wave * 64 + t * 16 + quad * 4 + r;
                int orig = perm[seg * NC + slot];
                float v = mx[t][r] + 2.0f;                // > 0: uint-monotone
                atomicMax(&maxs2enc[(size_t)seg * NC + orig],
                          __builtin_bit_cast(unsigned, v));
            }
    }
}

// ---------------------------------------------------------------------------
// loss: pos-distance from dbp bf16 columns (consistent rounding with the neg
// path), decode/merge the two direction maxes, weighted partials. grid = 128.
// ---------------------------------------------------------------------------
__global__ void loss_kernel(const float* __restrict__ att1, const float* __restrict__ att2,
                            const int* __restrict__ ids, const int* __restrict__ fp2,
                            const unsigned short* __restrict__ dbp,
                            const unsigned int* __restrict__ maxs2enc,
                            float* __restrict__ pnum, float* __restrict__ pden) {
    int b = blockIdx.x >> 3, chunk = blockIdx.x & 7;
    int tid = threadIdx.x;
    int n = chunk * 256 + tid;
    int idv = ids[b * NC + n];
    int i2 = fp2[b * 2 * NC + n], j2 = fp2[b * 2 * NC + NC + n];
    const uint4* a4 = (const uint4*)(dbp + ((size_t)(0 * BB + b) * HW + idv) * KHW);
    const uint4* b4 = (const uint4*)(dbp + ((size_t)(1 * BB + b) * HW + i2 * 64 + j2) * KHW);
    float dot = 0.f;
#pragma unroll
    for (int i = 0; i < 6; ++i) {                         // 6 x 16 B = 48 bf16
        uint4 xa = a4[i], xb = b4[i];
        const unsigned* xu = (const unsigned*)&xa;
        const unsigned* yu = (const unsigned*)&xb;
#pragma unroll
        for (int w = 0; w < 4; ++w) {
            float xl = __builtin_bit_cast(float, xu[w] << 16);
            float xh = __builtin_bit_cast(float, xu[w] & 0xffff0000u);
            float yl = __builtin_bit_cast(float, yu[w] << 16);
            float yh = __builtin_bit_cast(float, yu[w] & 0xffff0000u);
            dot = fmaf(xl, yl, fmaf(xh, yh, dot));
        }
    }
    float m0 = __builtin_bit_cast(float, maxs2enc[(size_t)(0 * BB + b) * NC + n]) - 2.0f;
    float m1 = __builtin_bit_cast(float, maxs2enc[(size_t)(1 * BB + b) * NC + n]) - 2.0f;
    float ms = fmaxf(m0, m1);
    float diff = (2.f - 2.f * dot) - (2.f - 2.f * ms);
    float w = att1[b * HW + idv] * att2[b * HW + i2 * 64 + j2];
    float num = w * fmaxf(0.f, 1.f + diff);
    float den = w;
    __shared__ float sn[256], sd[256];
    sn[tid] = num; sd[tid] = den;
    __syncthreads();
    for (int s = 128; s > 0; s >>= 1) {
        if (tid < s) { sn[tid] += sn[tid + s]; sd[tid] += sd[tid + s]; }
        __syncthreads();
    }
    if (tid == 0) { pnum[blockIdx.x] = sn[0]; pden[blockIdx.x] = sd[0]; }
}

__global__ void final_kernel(const float* __restrict__ pnum, const float* __restrict__ pden,
                             float* __restrict__ out) {
    int tid = threadIdx.x;
    __shared__ float r[16];
    if (tid < 16) {
        float n = 0.f, d = 0.f;
#pragma unroll
        for (int c = 0; c < 8; ++c) { n += pnum[tid * 8 + c]; d += pden[tid * 8 + c]; }
        r[tid] = n / d;
    }
    __syncthreads();
    if (tid == 0) {
        float s = 0.f;
#pragma unroll
        for (int k = 0; k < 16; ++k) s += r[k];
        out[0] = s * (1.f / BB);
    }
}

extern "C" void kernel_launch(void* const* d_in, const int* in_sizes, int n_in,
                              void* d_out, int out_size, void* d_ws, size_t ws_size,
                              hipStream_t stream) {
    const float* x1  = (const float*)d_in[0];
    const float* x2  = (const float*)d_in[1];
    const float* att1 = (const float*)d_in[2];
    const float* att2 = (const float*)d_in[3];
    const int* ids   = (const int*)d_in[4];
    const int* fp2   = (const int*)d_in[5];
    float* out = (float*)d_out;

    // ws layout (bytes), ~19.9 MB. (R8 finding: the harness poisons the FULL
    // d_ws allocation every iteration (~44 us) regardless of use.)
    unsigned char* w = (unsigned char*)d_ws;
    unsigned short* dbp = (unsigned short*)(w + 0);          // 2*16*4096*144 = 18,874,368
    int* perm    = (int*)(w + 18874368);                     // 32*2048*4 = 262,144
    int* qcol_s  = (int*)(w + 19136512);                     // 262,144
    int* aqpack  = (int*)(w + 19398656);                     // 262,144
    unsigned int* maxs2enc = (unsigned int*)(w + 19660800);  // 262,144
    float* pnum  = (float*)(w + 19922944);                   // 512
    float* pden  = (float*)(w + 19923456);                   // 512

    prep_fused<<<dim3(552), dim3(256), 0, stream>>>(x1, x2, ids, fp2, dbp,
                                                    perm, qcol_s, aqpack, maxs2enc);
    maxscore_mfma<<<dim3(1024), dim3(256), 0, stream>>>(dbp, perm, qcol_s, aqpack, maxs2enc);
    loss_kernel<<<dim3(128), dim3(256), 0, stream>>>(att1, att2, ids, fp2, dbp, maxs2enc, pnum, pden);
    final_kernel<<<dim3(1), dim3(64), 0, stream>>>(pnum, pden, out);
}